// Round 1
// baseline (3149.393 us; speedup 1.0000x reference)
//
#include <hip/hip_runtime.h>
#include <stdint.h>

// ---------------------------------------------------------------------------
// Binarized CNN (brevitas M5). Activations after bin_act are exactly +/-1,
// weights exactly +/-0.1  ->  layers 2/3/5 + FC are XNOR-popcount convs
// computed EXACTLY in integers. Only conv1 is a real fp32 conv.
// BN is training-mode: per-channel batch stats; computed via fused partials
// in the conv kernels + tiny reduce kernels.
// ---------------------------------------------------------------------------

constexpr int Bn  = 64;
constexpr int H1  = 3980;        // conv1 output rows
constexpr int J1  = 1990;        // after pool2x1
constexpr int H2o = 1991, J2 = 995;
constexpr int H3o = 994,  J3 = 497;
constexpr int H5o = 499,  J5 = 249;
constexpr int FCW = 249 * 8;     // u64 words per FC row (512*249 bits)

// ------------------------- weight binarization -----------------------------
// bit = 1  <=>  weight >= 0  <=>  +0.1      (activation bit = 1 <=> +1)
__global__ void binarize_all(const float* __restrict__ w2, const float* __restrict__ w3,
                             const float* __restrict__ w5, const float* __restrict__ wfc,
                             uint64_t* __restrict__ wb2, uint64_t* __restrict__ wb3,
                             uint64_t* __restrict__ wb5, uint64_t* __restrict__ wbf)
{
    int idx = blockIdx.x * 256 + threadIdx.x;
    if (idx < 1024) {                                  // w2: [128][128][4] -> [c][k][wdx]
        int wdx = idx & 1, k = (idx >> 1) & 3, c = idx >> 3;
        uint64_t v = 0;
        for (int ci = 0; ci < 64; ++ci)
            if (w2[((size_t)c * 128 + (wdx * 64 + ci)) * 4 + k] >= 0.f) v |= 1ull << ci;
        wb2[idx] = v;
    } else if (idx < 3072) {                           // w3: [256][128][4]
        int t = idx - 1024;
        int wdx = t & 1, k = (t >> 1) & 3, c = t >> 3;
        uint64_t v = 0;
        for (int ci = 0; ci < 64; ++ci)
            if (w3[((size_t)c * 128 + (wdx * 64 + ci)) * 4 + k] >= 0.f) v |= 1ull << ci;
        wb3[t] = v;
    } else if (idx < 9216) {                           // w5: [512][256][3]
        int t = idx - 3072;
        int wdx = t & 3, k = (t >> 2) % 3, c = t / 12;
        uint64_t v = 0;
        for (int ci = 0; ci < 64; ++ci)
            if (w5[((size_t)c * 256 + (wdx * 64 + ci)) * 3 + k] >= 0.f) v |= 1ull << ci;
        wb5[t] = v;
    } else if (idx < 9216 + 69720) {                   // wfc: [35][512*249] -> [oc][hh][wdx]
        int t = idx - 9216;
        int wdx = t & 7, hh = (t >> 3) % 249, oc = t / (249 * 8);
        uint64_t v = 0;
        for (int ci = 0; ci < 64; ++ci)
            if (wfc[(size_t)oc * 127488 + (size_t)(wdx * 64 + ci) * 249 + hh] >= 0.f)
                v |= 1ull << ci;
        wbf[t] = v;
    }
}

// ------------------------------- conv1 -------------------------------------
// x[64][16000] * sign(w1)[128][84] stride 4 -> y1, layout [n][cg=32][h][4c] (float4)
// Fused per-channel (sum, sumsq) partials per block.
__global__ __launch_bounds__(512) void conv1_kernel(
    const float* __restrict__ x, const float* __restrict__ w1,
    const float* __restrict__ b1, float* __restrict__ y1,
    float* __restrict__ part1)
{
    __shared__ float4 xs[1044];          // x[4*h0 .. 4*h0+4175] as float4
    __shared__ float  stat[256];         // [c][2] block partial sum/sumsq
    const int n    = blockIdx.y;
    const int h0   = blockIdx.x << 10;   // 1024 output rows per block
    const int tid  = threadIdx.x;
    const int wave = tid >> 6, lane = tid & 63;
    if (tid < 256) stat[tid] = 0.0f;
    const float4* x4 = (const float4*)x + (size_t)n * 4000;
    for (int i = tid; i < 1044; i += 512) {
        int gi = h0 + i;
        xs[i] = (gi < 4000) ? x4[gi] : make_float4(0.f, 0.f, 0.f, 0.f);
    }
    __syncthreads();

    const int hb = wave << 7;            // wave covers 128 rows (2 x 64)
    const int hA = h0 + hb + lane;
    const int hB = hA + 64;
    const bool vA = hA < H1, vB = hB < H1;

    for (int cg = 0; cg < 32; ++cg) {    // 4 channels per group
        float acc0[4] = {0.f, 0.f, 0.f, 0.f};
        float acc1[4] = {0.f, 0.f, 0.f, 0.f};
        const float* wrow = w1 + cg * 4 * 84;
        for (int kg = 0; kg < 21; ++kg) {           // k = 4*kg + jj, ascending
            float sw[4][4];                          // wave-uniform (SGPR)
            #pragma unroll
            for (int j = 0; j < 4; ++j)
                #pragma unroll
                for (int jj = 0; jj < 4; ++jj) {
                    float wv = wrow[j * 84 + kg * 4 + jj];
                    sw[j][jj] = (wv >= 0.f) ? 0.1f : -0.1f;
                }
            float4 xa = xs[hb + lane + kg];
            float4 xb = xs[hb + 64 + lane + kg];
            const float xav[4] = {xa.x, xa.y, xa.z, xa.w};
            const float xbv[4] = {xb.x, xb.y, xb.z, xb.w};
            #pragma unroll
            for (int jj = 0; jj < 4; ++jj)
                #pragma unroll
                for (int j = 0; j < 4; ++j) {
                    acc0[j] = fmaf(sw[j][jj], xav[jj], acc0[j]);
                    acc1[j] = fmaf(sw[j][jj], xbv[jj], acc1[j]);
                }
        }
        float4 o0, o1;
        float bs[4], bq[4];
        #pragma unroll
        for (int j = 0; j < 4; ++j) {
            float bv = b1[cg * 4 + j];
            float v0 = acc0[j] + bv;
            float v1 = acc1[j] + bv;
            (&o0.x)[j] = v0; (&o1.x)[j] = v1;
            float s = 0.f, q = 0.f;
            if (vA) { s += v0; q = fmaf(v0, v0, q); }
            if (vB) { s += v1; q = fmaf(v1, v1, q); }
            bs[j] = s; bq[j] = q;
        }
        float4* yrow = (float4*)y1 + ((size_t)n * 32 + cg) * H1;
        if (vA) yrow[hA] = o0;
        if (vB) yrow[hB] = o1;
        #pragma unroll
        for (int j = 0; j < 4; ++j)
            for (int o = 32; o > 0; o >>= 1) {
                bs[j] += __shfl_xor(bs[j], o, 64);
                bq[j] += __shfl_xor(bq[j], o, 64);
            }
        if (lane == 0)
            #pragma unroll
            for (int j = 0; j < 4; ++j) {
                atomicAdd(&stat[(cg * 4 + j) * 2 + 0], bs[j]);
                atomicAdd(&stat[(cg * 4 + j) * 2 + 1], bq[j]);
            }
    }
    __syncthreads();
    if (tid < 256)
        part1[(size_t)(n * gridDim.x + blockIdx.x) * 256 + tid] = stat[tid];
}

__global__ void bn_reduce1(const float* __restrict__ part1, float2* __restrict__ bnp)
{
    int c = threadIdx.x;                         // 128 threads
    double S = 0.0, SS = 0.0;
    for (int b = 0; b < 256; ++b) {
        S  += (double)part1[(size_t)b * 256 + c * 2 + 0];
        SS += (double)part1[(size_t)b * 256 + c * 2 + 1];
    }
    const double N = (double)Bn * H1;
    double mu  = S / N;
    double var = SS / N - mu * mu;
    bnp[c] = make_float2((float)mu, (float)(1.0 / sqrt(var + 1e-5)));
}

// sign(BN(y)) then maxpool(2,1) then bitpack via wave ballot (lane = channel)
__global__ void signpool1(const float* __restrict__ y1, const float2* __restrict__ bnp,
                          const float* __restrict__ g, const float* __restrict__ be,
                          uint64_t* __restrict__ a1)
{
    const int n  = blockIdx.y;
    const int j0 = blockIdx.x << 6;
    const int w = threadIdx.x >> 6, lane = threadIdx.x & 63;   // block=128: 2 words
    const int c = (w << 6) + lane;
    const float2 mi = bnp[c];
    const float gg = g[c], bb = be[c];
    const float* yc = y1 + ((size_t)n * 32 + (c >> 2)) * (size_t)H1 * 4 + (c & 3);
    const int jend = min(j0 + 64, J1);
    for (int j = j0; j < jend; ++j) {
        float v0 = yc[(size_t)(2 * j) * 4];
        float v1 = yc[(size_t)(2 * j + 1) * 4];
        // match ref op order: ((y-mu)*inv)*g + be, separate roundings
        float t0 = __fadd_rn(__fmul_rn(__fmul_rn(__fsub_rn(v0, mi.x), mi.y), gg), bb);
        float t1 = __fadd_rn(__fmul_rn(__fmul_rn(__fsub_rn(v1, mi.x), mi.y), gg), bb);
        uint64_t word = __ballot((t0 >= 0.f) || (t1 >= 0.f));
        if (lane == 0) a1[((size_t)n * J1 + j) * 2 + w] = word;
    }
}

// --------------------------- binary convs ----------------------------------
// q = 64*CINW*V - 2*popc(a xor w) over valid taps; y = 0.1*q + b (exact int q)
template<int CINW, int KK, int PAD, int COUT>
__global__ __launch_bounds__(COUT) void bconv(
    const uint64_t* __restrict__ ain, const uint64_t* __restrict__ wb,
    const int HIN, const int HOUT,
    int16_t* __restrict__ qout, int* __restrict__ part)
{
    __shared__ uint64_t rows[(64 + KK - 1) * CINW];
    const int n  = blockIdx.y;
    const int h0 = blockIdx.x << 6;
    const int c  = threadIdx.x;
    for (int i = c; i < (64 + KK - 1) * CINW; i += COUT) {
        int r = h0 - PAD + i / CINW;
        rows[i] = (r >= 0 && r < HIN) ? ain[((size_t)n * HIN + r) * CINW + (i % CINW)] : 0ull;
    }
    __syncthreads();
    uint64_t wreg[KK * CINW];
    #pragma unroll
    for (int i = 0; i < KK * CINW; ++i) wreg[i] = wb[(size_t)c * KK * CINW + i];
    int sq = 0, sq2 = 0;
    const int hmax = min(64, HOUT - h0);
    for (int i = 0; i < hmax; ++i) {
        const int h   = h0 + i;
        const int klo = max(0, PAD - h);
        const int khi = min(KK, HIN + PAD - h);
        int X = 0;
        if (klo == 0 && khi == KK) {
            #pragma unroll
            for (int k = 0; k < KK; ++k)
                #pragma unroll
                for (int wd = 0; wd < CINW; ++wd)
                    X += __popcll(rows[(i + k) * CINW + wd] ^ wreg[k * CINW + wd]);
        } else {
            for (int k = klo; k < khi; ++k)
                #pragma unroll
                for (int wd = 0; wd < CINW; ++wd)
                    X += __popcll(rows[(i + k) * CINW + wd] ^ wreg[k * CINW + wd]);
        }
        const int q = 64 * CINW * (khi - klo) - 2 * X;
        qout[((size_t)n * HOUT + h) * COUT + c] = (int16_t)q;
        sq += q; sq2 += q * q;
    }
    const size_t blk = (size_t)n * gridDim.x + blockIdx.x;
    part[(blk * COUT + c) * 2 + 0] = sq;
    part[(blk * COUT + c) * 2 + 1] = sq2;
}

__global__ void bn_reduce_q(const int* __restrict__ part, const int nblk, const int C,
                            const double N, const float* __restrict__ bias,
                            float2* __restrict__ bnp)
{
    const int c = blockIdx.x * blockDim.x + threadIdx.x;
    if (c >= C) return;
    long long Sq = 0, Sq2 = 0;
    for (int b = 0; b < nblk; ++b) {
        Sq  += part[((size_t)b * C + c) * 2 + 0];
        Sq2 += part[((size_t)b * C + c) * 2 + 1];
    }
    const double bb = (double)bias[c];
    const double S  = 0.1 * (double)Sq + N * bb;                 // sum(y), exact
    const double SS = 0.01 * (double)Sq2 + 0.2 * bb * (double)Sq + N * bb * bb;
    const double mu = S / N;
    const double var = SS / N - mu * mu;
    bnp[c] = make_float2((float)mu, (float)(1.0 / sqrt(var + 1e-5)));
}

template<int W>
__global__ void signpool_q(const int16_t* __restrict__ q, const float* __restrict__ bias,
                           const float2* __restrict__ bnp, const float* __restrict__ g,
                           const float* __restrict__ be, const int H, const int J,
                           uint64_t* __restrict__ aout)
{
    const int n  = blockIdx.y;
    const int j0 = blockIdx.x << 6;
    const int wave = threadIdx.x >> 6, lane = threadIdx.x & 63;
    const int nw = blockDim.x >> 6;
    const int C  = W * 64;
    const int jend = min(j0 + 64, J);
    for (int w = wave; w < W; w += nw) {
        const int c = (w << 6) + lane;
        const float2 mi = bnp[c];
        const float bb = bias[c], gg = g[c], bbe = be[c];
        for (int j = j0; j < jend; ++j) {
            float y0 = __fadd_rn(__fmul_rn(0.1f, (float)q[((size_t)n * H + 2 * j    ) * C + c]), bb);
            float y1v= __fadd_rn(__fmul_rn(0.1f, (float)q[((size_t)n * H + 2 * j + 1) * C + c]), bb);
            float t0 = __fadd_rn(__fmul_rn(__fmul_rn(__fsub_rn(y0,  mi.x), mi.y), gg), bbe);
            float t1 = __fadd_rn(__fmul_rn(__fmul_rn(__fsub_rn(y1v, mi.x), mi.y), gg), bbe);
            uint64_t word = __ballot((t0 >= 0.f) || (t1 >= 0.f));
            if (lane == 0) aout[((size_t)n * J + j) * W + w] = word;
        }
    }
}

// ------------------------------- FC ----------------------------------------
__global__ void fc_kernel(const uint64_t* __restrict__ a5, const uint64_t* __restrict__ wfcb,
                          float* __restrict__ out)
{
    const int n    = blockIdx.y;
    const int oc   = blockIdx.x * 4 + (threadIdx.x >> 6);
    const int lane = threadIdx.x & 63;
    if (oc >= 35) return;
    const uint64_t* arow = a5   + (size_t)n  * FCW;
    const uint64_t* wrow = wfcb + (size_t)oc * FCW;
    int X = 0;
    for (int i = lane; i < FCW; i += 64)
        X += __popcll(arow[i] ^ wrow[i]);
    for (int o = 32; o > 0; o >>= 1) X += __shfl_xor(X, o, 64);
    if (lane == 0) out[(size_t)n * 35 + oc] = 0.1f * (float)(127488 - 2 * X);
}

// ---------------------------------------------------------------------------
extern "C" void kernel_launch(void* const* d_in, const int* in_sizes, int n_in,
                              void* d_out, int out_size, void* d_ws, size_t ws_size,
                              hipStream_t stream)
{
    (void)in_sizes; (void)n_in; (void)out_size;
    const float* x   = (const float*)d_in[0];
    const float* w1  = (const float*)d_in[1];
    const float* b1  = (const float*)d_in[2];
    const float* g1  = (const float*)d_in[3];
    const float* be1 = (const float*)d_in[4];
    const float* w2  = (const float*)d_in[5];
    const float* b2  = (const float*)d_in[6];
    const float* g2  = (const float*)d_in[7];
    const float* be2 = (const float*)d_in[8];
    const float* w3  = (const float*)d_in[9];
    const float* b3  = (const float*)d_in[10];
    const float* g3  = (const float*)d_in[11];
    const float* be3 = (const float*)d_in[12];
    const float* w5  = (const float*)d_in[13];
    const float* b5  = (const float*)d_in[14];
    const float* g5  = (const float*)d_in[15];
    const float* be5 = (const float*)d_in[16];
    const float* wfc = (const float*)d_in[17];
    char* ws = (char*)d_ws;

    size_t cur = 0;
    auto take = [&](size_t bytes) {
        size_t r = cur;
        cur = (cur + bytes + 255) & ~(size_t)255;
        return r;
    };
    // y1 region (130.4 MB) is reused after signpool1: i16 q-buffer (<=32.7 MB)
    // at offset 0 and int partials (2 MB) at +34 MB.
    const size_t off_y1 = take(130416640);
    float*    y1 = (float*)(ws + off_y1);
    int16_t*  qb = (int16_t*)(ws + off_y1);
    int*      pq = (int*)(ws + off_y1 + 35651584);
    uint64_t* a1  = (uint64_t*)(ws + take(2037760));
    uint64_t* a2  = (uint64_t*)(ws + take(1018880));
    uint64_t* a3  = (uint64_t*)(ws + take(1017856));
    uint64_t* a5  = (uint64_t*)(ws + take(1019904));
    uint64_t* wb2 = (uint64_t*)(ws + take(8192));
    uint64_t* wb3 = (uint64_t*)(ws + take(16384));
    uint64_t* wb5 = (uint64_t*)(ws + take(49152));
    uint64_t* wbf = (uint64_t*)(ws + take(557760));
    float*    p1  = (float*)(ws + take(262144));
    float2*   bnp1 = (float2*)(ws + take(1024));
    float2*   bnp2 = (float2*)(ws + take(1024));
    float2*   bnp3 = (float2*)(ws + take(2048));
    float2*   bnp5 = (float2*)(ws + take(4096));
    if (cur > ws_size) return;   // insufficient workspace -> fail loudly

    hipLaunchKernelGGL(binarize_all, dim3(309), dim3(256), 0, stream,
                       w2, w3, w5, wfc, wb2, wb3, wb5, wbf);
    hipLaunchKernelGGL(conv1_kernel, dim3(4, 64), dim3(512), 0, stream,
                       x, w1, b1, y1, p1);
    hipLaunchKernelGGL(bn_reduce1, dim3(1), dim3(128), 0, stream, p1, bnp1);
    hipLaunchKernelGGL(signpool1, dim3(32, 64), dim3(128), 0, stream,
                       y1, bnp1, g1, be1, a1);
    hipLaunchKernelGGL((bconv<2, 4, 2, 128>), dim3(32, 64), dim3(128), 0, stream,
                       a1, wb2, J1, H2o, qb, pq);
    hipLaunchKernelGGL(bn_reduce_q, dim3(1), dim3(128), 0, stream,
                       pq, 2048, 128, (double)Bn * H2o, b2, bnp2);
    hipLaunchKernelGGL((signpool_q<2>), dim3(16, 64), dim3(128), 0, stream,
                       qb, b2, bnp2, g2, be2, H2o, J2, a2);
    hipLaunchKernelGGL((bconv<2, 4, 1, 256>), dim3(16, 64), dim3(256), 0, stream,
                       a2, wb3, J2, H3o, qb, pq);
    hipLaunchKernelGGL(bn_reduce_q, dim3(1), dim3(256), 0, stream,
                       pq, 1024, 256, (double)Bn * H3o, b3, bnp3);
    hipLaunchKernelGGL((signpool_q<4>), dim3(8, 64), dim3(256), 0, stream,
                       qb, b3, bnp3, g3, be3, H3o, J3, a3);
    hipLaunchKernelGGL((bconv<4, 3, 2, 512>), dim3(8, 64), dim3(512), 0, stream,
                       a3, wb5, J3, H5o, qb, pq);
    hipLaunchKernelGGL(bn_reduce_q, dim3(1), dim3(512), 0, stream,
                       pq, 512, 512, (double)Bn * H5o, b5, bnp5);
    hipLaunchKernelGGL((signpool_q<8>), dim3(4, 64), dim3(256), 0, stream,
                       qb, b5, bnp5, g5, be5, H5o, J5, a5);
    hipLaunchKernelGGL(fc_kernel, dim3(9, 64), dim3(256), 0, stream,
                       a5, wbf, (float*)d_out);
}

// Round 2
// 1587.367 us; speedup vs baseline: 1.9840x; 1.9840x over previous
//
#include <hip/hip_runtime.h>
#include <stdint.h>

// ---------------------------------------------------------------------------
// Binarized CNN (brevitas M5). Activations after bin_act are exactly +/-1,
// weights exactly +/-0.1  ->  layers 2/3/5 + FC are XNOR-popcount convs
// computed EXACTLY in integers. Only conv1 is a real fp32 conv.
// Stage 1 is computed TWICE (stats pass, then sign pass) so the 130 MB y1
// tensor is never materialized (R1 counters: y1 round-trip cost 6.1 GB HBM).
// ---------------------------------------------------------------------------

constexpr int Bn  = 64;
constexpr int H1  = 3980;        // conv1 output rows
constexpr int J1  = 1990;        // after pool2x1
constexpr int H2o = 1991, J2 = 995;
constexpr int H3o = 994,  J3 = 497;
constexpr int H5o = 499,  J5 = 249;
constexpr int FCW = 249 * 8;     // u64 words per FC row (512*249 bits)

// ------------------------- weight binarization -----------------------------
// bit = 1  <=>  weight >= 0  <=>  +0.1      (activation bit = 1 <=> +1)
__global__ void binarize_all(const float* __restrict__ w2, const float* __restrict__ w3,
                             const float* __restrict__ w5, const float* __restrict__ wfc,
                             uint64_t* __restrict__ wb2, uint64_t* __restrict__ wb3,
                             uint64_t* __restrict__ wb5, uint64_t* __restrict__ wbf)
{
    int idx = blockIdx.x * 256 + threadIdx.x;
    if (idx < 1024) {                                  // w2: [128][128][4] -> [c][k][wdx]
        int wdx = idx & 1, k = (idx >> 1) & 3, c = idx >> 3;
        uint64_t v = 0;
        for (int ci = 0; ci < 64; ++ci)
            if (w2[((size_t)c * 128 + (wdx * 64 + ci)) * 4 + k] >= 0.f) v |= 1ull << ci;
        wb2[idx] = v;
    } else if (idx < 3072) {                           // w3: [256][128][4]
        int t = idx - 1024;
        int wdx = t & 1, k = (t >> 1) & 3, c = t >> 3;
        uint64_t v = 0;
        for (int ci = 0; ci < 64; ++ci)
            if (w3[((size_t)c * 128 + (wdx * 64 + ci)) * 4 + k] >= 0.f) v |= 1ull << ci;
        wb3[t] = v;
    } else if (idx < 9216) {                           // w5: [512][256][3]
        int t = idx - 3072;
        int wdx = t & 3, k = (t >> 2) % 3, c = t / 12;
        uint64_t v = 0;
        for (int ci = 0; ci < 64; ++ci)
            if (w5[((size_t)c * 256 + (wdx * 64 + ci)) * 3 + k] >= 0.f) v |= 1ull << ci;
        wb5[t] = v;
    } else if (idx < 9216 + 69720) {                   // wfc: [35][512*249] -> [oc][hh][wdx]
        int t = idx - 9216;
        int wdx = t & 7, hh = (t >> 3) % 249, oc = t / (249 * 8);
        uint64_t v = 0;
        for (int ci = 0; ci < 64; ++ci)
            if (wfc[(size_t)oc * 127488 + (size_t)(wdx * 64 + ci) * 249 + hh] >= 0.f)
                v |= 1ull << ci;
        wbf[t] = v;
    }
}

// ------------------------------- stage 1 ------------------------------------
// Fused conv1 (stride 4, K=84) computed per row-pair j (rows 2j, 2j+1).
// sign_mode==0: per-channel (sum, sumsq) partials (deterministic wave slices).
// sign_mode==1: BN (exact ref rounding order) + sign + maxpool(2,1) + bitpack;
//               lane j accumulates its 64-channel word in a register.
// blockIdx.z selects the channel half (word): cg in [16z, 16z+16).
__global__ __launch_bounds__(256) void conv1_fused(
    const float* __restrict__ x, const float* __restrict__ w1,
    const float* __restrict__ b1, const float2* __restrict__ bnp,
    const float* __restrict__ g, const float* __restrict__ be,
    float* __restrict__ part, uint64_t* __restrict__ a1, const int sign_mode)
{
    __shared__ float4 xe[268], xo[268];     // x4 even/odd split: lane stride 16 B
    __shared__ float  statw[4][128];        // per-wave (sum,sumsq) slices
    const int n    = blockIdx.y;
    const int j0   = blockIdx.x << 8;       // 256 row-pairs per block
    const int z    = blockIdx.z;            // channel word (0/1)
    const int tid  = threadIdx.x;
    const int wave = tid >> 6, lane = tid & 63;

    if (!sign_mode)
        for (int i = tid; i < 512; i += 256) ((float*)statw)[i] = 0.f;

    const float4* x4 = (const float4*)x + (size_t)n * 4000;
    for (int i = tid; i < 532; i += 256) {
        int gi = 2 * j0 + i;
        float4 v = (gi < 4000) ? x4[gi] : make_float4(0.f, 0.f, 0.f, 0.f);
        if (i & 1) xo[i >> 1] = v; else xe[i >> 1] = v;
    }
    __syncthreads();

    const int  jl    = tid;
    const int  j     = j0 + jl;
    const bool valid = j < J1;
    uint64_t bits = 0;

    for (int cgi = 0; cgi < 16; ++cgi) {
        const int cg = z * 16 + cgi;
        float acc0[4] = {0.f, 0.f, 0.f, 0.f};
        float acc1[4] = {0.f, 0.f, 0.f, 0.f};
        const float* wrow = w1 + cg * 4 * 84;
        #pragma unroll
        for (int kg = 0; kg < 21; ++kg) {
            float sw[4][4];                              // block-uniform (SGPR)
            #pragma unroll
            for (int ch = 0; ch < 4; ++ch)
                #pragma unroll
                for (int jj = 0; jj < 4; ++jj) {
                    float wv = wrow[ch * 84 + kg * 4 + jj];
                    sw[ch][jj] = (wv >= 0.f) ? 0.1f : -0.1f;
                }
            float4 xa, xb;                               // row 2j tap / row 2j+1 tap
            if (kg & 1) { xa = xo[jl + (kg - 1) / 2]; xb = xe[jl + (kg + 1) / 2]; }
            else        { xa = xe[jl + kg / 2];       xb = xo[jl + kg / 2]; }
            const float xav[4] = {xa.x, xa.y, xa.z, xa.w};
            const float xbv[4] = {xb.x, xb.y, xb.z, xb.w};
            #pragma unroll
            for (int jj = 0; jj < 4; ++jj)               // same chain order as R1
                #pragma unroll
                for (int ch = 0; ch < 4; ++ch) {
                    acc0[ch] = fmaf(sw[ch][jj], xav[jj], acc0[ch]);
                    acc1[ch] = fmaf(sw[ch][jj], xbv[jj], acc1[ch]);
                }
        }
        #pragma unroll
        for (int ch = 0; ch < 4; ++ch) {
            const int c = cg * 4 + ch;
            const float bv = b1[c];
            float v0 = acc0[ch] + bv;
            float v1 = acc1[ch] + bv;
            if (!valid) { v0 = 0.f; v1 = 0.f; }
            if (sign_mode) {
                const float2 mi = bnp[c];
                const float gg = g[c], bbe = be[c];
                float t0 = __fadd_rn(__fmul_rn(__fmul_rn(__fsub_rn(v0, mi.x), mi.y), gg), bbe);
                float t1 = __fadd_rn(__fmul_rn(__fmul_rn(__fsub_rn(v1, mi.x), mi.y), gg), bbe);
                if ((t0 >= 0.f) || (t1 >= 0.f)) bits |= 1ull << (c & 63);
            } else {
                float s = v0 + v1;
                float q = fmaf(v1, v1, fmaf(v0, v0, 0.f));
                #pragma unroll
                for (int o = 32; o > 0; o >>= 1) {
                    s += __shfl_xor(s, o, 64);
                    q += __shfl_xor(q, o, 64);
                }
                if (lane == 0) {
                    statw[wave][(cgi * 4 + ch) * 2 + 0] += s;
                    statw[wave][(cgi * 4 + ch) * 2 + 1] += q;
                }
            }
        }
    }

    if (sign_mode) {
        if (valid) a1[((size_t)n * J1 + j) * 2 + z] = bits;
    } else {
        __syncthreads();
        if (tid < 128) {
            float v = ((statw[0][tid] + statw[1][tid]) + statw[2][tid]) + statw[3][tid];
            part[((size_t)((n * 8 + blockIdx.x) * 2 + z)) * 128 + tid] = v;
        }
    }
}

__global__ void bn_reduce1(const float* __restrict__ part, float2* __restrict__ bnp)
{
    const int c = threadIdx.x;                   // 128 threads
    const int z = c >> 6, cl = c & 63;
    double S = 0.0, SS = 0.0;
    for (int b = 0; b < 512; ++b) {
        const float* p = part + ((size_t)(b * 2 + z)) * 128 + cl * 2;
        S  += (double)p[0];
        SS += (double)p[1];
    }
    const double N = (double)Bn * H1;
    double mu  = S / N;
    double var = SS / N - mu * mu;
    bnp[c] = make_float2((float)mu, (float)(1.0 / sqrt(var + 1e-5)));
}

// --------------------------- binary convs ----------------------------------
// q = 64*CINW*V - 2*popc(a xor w) over valid taps; y = 0.1*q + b (exact int q)
template<int CINW, int KK, int PAD, int COUT>
__global__ __launch_bounds__(COUT) void bconv(
    const uint64_t* __restrict__ ain, const uint64_t* __restrict__ wb,
    const int HIN, const int HOUT,
    int16_t* __restrict__ qout, int* __restrict__ part)
{
    __shared__ uint64_t rows[(64 + KK - 1) * CINW];
    const int n  = blockIdx.y;
    const int h0 = blockIdx.x << 6;
    const int c  = threadIdx.x;
    for (int i = c; i < (64 + KK - 1) * CINW; i += COUT) {
        int r = h0 - PAD + i / CINW;
        rows[i] = (r >= 0 && r < HIN) ? ain[((size_t)n * HIN + r) * CINW + (i % CINW)] : 0ull;
    }
    __syncthreads();
    uint64_t wreg[KK * CINW];
    #pragma unroll
    for (int i = 0; i < KK * CINW; ++i) wreg[i] = wb[(size_t)c * KK * CINW + i];
    int sq = 0, sq2 = 0;
    const int hmax = min(64, HOUT - h0);
    for (int i = 0; i < hmax; ++i) {
        const int h   = h0 + i;
        const int klo = max(0, PAD - h);
        const int khi = min(KK, HIN + PAD - h);
        int X = 0;
        if (klo == 0 && khi == KK) {
            #pragma unroll
            for (int k = 0; k < KK; ++k)
                #pragma unroll
                for (int wd = 0; wd < CINW; ++wd)
                    X += __popcll(rows[(i + k) * CINW + wd] ^ wreg[k * CINW + wd]);
        } else {
            for (int k = klo; k < khi; ++k)
                #pragma unroll
                for (int wd = 0; wd < CINW; ++wd)
                    X += __popcll(rows[(i + k) * CINW + wd] ^ wreg[k * CINW + wd]);
        }
        const int q = 64 * CINW * (khi - klo) - 2 * X;
        qout[((size_t)n * HOUT + h) * COUT + c] = (int16_t)q;
        sq += q; sq2 += q * q;
    }
    const size_t blk = (size_t)n * gridDim.x + blockIdx.x;
    part[(blk * COUT + c) * 2 + 0] = sq;
    part[(blk * COUT + c) * 2 + 1] = sq2;
}

__global__ void bn_reduce_q(const int* __restrict__ part, const int nblk, const int C,
                            const double N, const float* __restrict__ bias,
                            float2* __restrict__ bnp)
{
    const int c = blockIdx.x * blockDim.x + threadIdx.x;
    if (c >= C) return;
    long long Sq = 0, Sq2 = 0;
    for (int b = 0; b < nblk; ++b) {
        Sq  += part[((size_t)b * C + c) * 2 + 0];
        Sq2 += part[((size_t)b * C + c) * 2 + 1];
    }
    const double bb = (double)bias[c];
    const double S  = 0.1 * (double)Sq + N * bb;                 // sum(y), exact
    const double SS = 0.01 * (double)Sq2 + 0.2 * bb * (double)Sq + N * bb * bb;
    const double mu = S / N;
    const double var = SS / N - mu * mu;
    bnp[c] = make_float2((float)mu, (float)(1.0 / sqrt(var + 1e-5)));
}

template<int W>
__global__ void signpool_q(const int16_t* __restrict__ q, const float* __restrict__ bias,
                           const float2* __restrict__ bnp, const float* __restrict__ g,
                           const float* __restrict__ be, const int H, const int J,
                           uint64_t* __restrict__ aout)
{
    const int n  = blockIdx.y;
    const int j0 = blockIdx.x << 6;
    const int wave = threadIdx.x >> 6, lane = threadIdx.x & 63;
    const int nw = blockDim.x >> 6;
    const int C  = W * 64;
    const int jend = min(j0 + 64, J);
    for (int w = wave; w < W; w += nw) {
        const int c = (w << 6) + lane;
        const float2 mi = bnp[c];
        const float bb = bias[c], gg = g[c], bbe = be[c];
        for (int j = j0; j < jend; ++j) {
            float y0 = __fadd_rn(__fmul_rn(0.1f, (float)q[((size_t)n * H + 2 * j    ) * C + c]), bb);
            float y1v= __fadd_rn(__fmul_rn(0.1f, (float)q[((size_t)n * H + 2 * j + 1) * C + c]), bb);
            float t0 = __fadd_rn(__fmul_rn(__fmul_rn(__fsub_rn(y0,  mi.x), mi.y), gg), bbe);
            float t1 = __fadd_rn(__fmul_rn(__fmul_rn(__fsub_rn(y1v, mi.x), mi.y), gg), bbe);
            uint64_t word = __ballot((t0 >= 0.f) || (t1 >= 0.f));
            if (lane == 0) aout[((size_t)n * J + j) * W + w] = word;
        }
    }
}

// ------------------------------- FC ----------------------------------------
__global__ void fc_kernel(const uint64_t* __restrict__ a5, const uint64_t* __restrict__ wfcb,
                          float* __restrict__ out)
{
    const int n    = blockIdx.y;
    const int oc   = blockIdx.x * 4 + (threadIdx.x >> 6);
    const int lane = threadIdx.x & 63;
    if (oc >= 35) return;
    const uint64_t* arow = a5   + (size_t)n  * FCW;
    const uint64_t* wrow = wfcb + (size_t)oc * FCW;
    int X = 0;
    for (int i = lane; i < FCW; i += 64)
        X += __popcll(arow[i] ^ wrow[i]);
    for (int o = 32; o > 0; o >>= 1) X += __shfl_xor(X, o, 64);
    if (lane == 0) out[(size_t)n * 35 + oc] = 0.1f * (float)(127488 - 2 * X);
}

// ---------------------------------------------------------------------------
extern "C" void kernel_launch(void* const* d_in, const int* in_sizes, int n_in,
                              void* d_out, int out_size, void* d_ws, size_t ws_size,
                              hipStream_t stream)
{
    (void)in_sizes; (void)n_in; (void)out_size;
    const float* x   = (const float*)d_in[0];
    const float* w1  = (const float*)d_in[1];
    const float* b1  = (const float*)d_in[2];
    const float* g1  = (const float*)d_in[3];
    const float* be1 = (const float*)d_in[4];
    const float* w2  = (const float*)d_in[5];
    const float* b2  = (const float*)d_in[6];
    const float* g2  = (const float*)d_in[7];
    const float* be2 = (const float*)d_in[8];
    const float* w3  = (const float*)d_in[9];
    const float* b3  = (const float*)d_in[10];
    const float* g3  = (const float*)d_in[11];
    const float* be3 = (const float*)d_in[12];
    const float* w5  = (const float*)d_in[13];
    const float* b5  = (const float*)d_in[14];
    const float* g5  = (const float*)d_in[15];
    const float* be5 = (const float*)d_in[16];
    const float* wfc = (const float*)d_in[17];
    char* ws = (char*)d_ws;

    size_t cur = 0;
    auto take = [&](size_t bytes) {
        size_t r = cur;
        cur = (cur + bytes + 255) & ~(size_t)255;
        return r;
    };
    int16_t*  qb  = (int16_t*)(ws + take(33554432));   // stage q buffer (<=32.7 MB)
    int*      pq  = (int*)(ws + take(4194304));        // bconv stat partials
    uint64_t* a1  = (uint64_t*)(ws + take(2037760));
    uint64_t* a2  = (uint64_t*)(ws + take(1018880));
    uint64_t* a3  = (uint64_t*)(ws + take(1017856));
    uint64_t* a5  = (uint64_t*)(ws + take(1019904));
    uint64_t* wb2 = (uint64_t*)(ws + take(8192));
    uint64_t* wb3 = (uint64_t*)(ws + take(16384));
    uint64_t* wb5 = (uint64_t*)(ws + take(49152));
    uint64_t* wbf = (uint64_t*)(ws + take(557760));
    float*    p1  = (float*)(ws + take(524288));       // 1024 blocks x 128 floats
    float2*   bnp1 = (float2*)(ws + take(1024));
    float2*   bnp2 = (float2*)(ws + take(1024));
    float2*   bnp3 = (float2*)(ws + take(2048));
    float2*   bnp5 = (float2*)(ws + take(4096));
    if (cur > ws_size) return;   // insufficient workspace -> fail loudly

    hipLaunchKernelGGL(binarize_all, dim3(309), dim3(256), 0, stream,
                       w2, w3, w5, wfc, wb2, wb3, wb5, wbf);
    // stage 1: stats pass, reduce, sign pass (no y1 materialization)
    hipLaunchKernelGGL(conv1_fused, dim3(8, 64, 2), dim3(256), 0, stream,
                       x, w1, b1, (const float2*)nullptr, g1, be1, p1, a1, 0);
    hipLaunchKernelGGL(bn_reduce1, dim3(1), dim3(128), 0, stream, p1, bnp1);
    hipLaunchKernelGGL(conv1_fused, dim3(8, 64, 2), dim3(256), 0, stream,
                       x, w1, b1, bnp1, g1, be1, p1, a1, 1);
    // stage 2
    hipLaunchKernelGGL((bconv<2, 4, 2, 128>), dim3(32, 64), dim3(128), 0, stream,
                       a1, wb2, J1, H2o, qb, pq);
    hipLaunchKernelGGL(bn_reduce_q, dim3(1), dim3(128), 0, stream,
                       pq, 2048, 128, (double)Bn * H2o, b2, bnp2);
    hipLaunchKernelGGL((signpool_q<2>), dim3(16, 64), dim3(128), 0, stream,
                       qb, b2, bnp2, g2, be2, H2o, J2, a2);
    // stage 3
    hipLaunchKernelGGL((bconv<2, 4, 1, 256>), dim3(16, 64), dim3(256), 0, stream,
                       a2, wb3, J2, H3o, qb, pq);
    hipLaunchKernelGGL(bn_reduce_q, dim3(1), dim3(256), 0, stream,
                       pq, 1024, 256, (double)Bn * H3o, b3, bnp3);
    hipLaunchKernelGGL((signpool_q<4>), dim3(8, 64), dim3(256), 0, stream,
                       qb, b3, bnp3, g3, be3, H3o, J3, a3);
    // stage 5
    hipLaunchKernelGGL((bconv<4, 3, 2, 512>), dim3(8, 64), dim3(512), 0, stream,
                       a3, wb5, J3, H5o, qb, pq);
    hipLaunchKernelGGL(bn_reduce_q, dim3(1), dim3(512), 0, stream,
                       pq, 512, 512, (double)Bn * H5o, b5, bnp5);
    hipLaunchKernelGGL((signpool_q<8>), dim3(4, 64), dim3(256), 0, stream,
                       qb, b5, bnp5, g5, be5, H5o, J5, a5);
    // FC
    hipLaunchKernelGGL(fc_kernel, dim3(9, 64), dim3(256), 0, stream,
                       a5, wbf, (float*)d_out);
}

// Round 3
// 682.819 us; speedup vs baseline: 4.6123x; 2.3247x over previous
//
#include <hip/hip_runtime.h>
#include <stdint.h>

// ---------------------------------------------------------------------------
// Binarized CNN (brevitas M5). Activations after bin_act are exactly +/-1,
// weights exactly +/-0.1  ->  layers 2/3/5 + FC are XNOR-popcount convs
// computed EXACTLY in integers. Only conv1 is a real fp32 conv.
// Stage 1 is computed TWICE (stats pass, then sign pass) so the 130 MB y1
// tensor is never materialized. R2 fix: BN stat reductions are parallel
// (one block/channel, tree reduce) -- the serial 1-block versions were
// ~535 us each, latency-bound (R2 rocprof).
// ---------------------------------------------------------------------------

constexpr int Bn  = 64;
constexpr int H1  = 3980;        // conv1 output rows
constexpr int J1  = 1990;        // after pool2x1
constexpr int H2o = 1991, J2 = 995;
constexpr int H3o = 994,  J3 = 497;
constexpr int H5o = 499,  J5 = 249;
constexpr int FCW = 249 * 8;     // u64 words per FC row (512*249 bits)

// ------------------------- weight binarization -----------------------------
// bit = 1  <=>  weight >= 0  <=>  +0.1      (activation bit = 1 <=> +1)
__global__ void binarize_all(const float* __restrict__ w2, const float* __restrict__ w3,
                             const float* __restrict__ w5, const float* __restrict__ wfc,
                             uint64_t* __restrict__ wb2, uint64_t* __restrict__ wb3,
                             uint64_t* __restrict__ wb5, uint64_t* __restrict__ wbf)
{
    int idx = blockIdx.x * 256 + threadIdx.x;
    if (idx < 1024) {                                  // w2: [128][128][4] -> [c][k][wdx]
        int wdx = idx & 1, k = (idx >> 1) & 3, c = idx >> 3;
        uint64_t v = 0;
        for (int ci = 0; ci < 64; ++ci)
            if (w2[((size_t)c * 128 + (wdx * 64 + ci)) * 4 + k] >= 0.f) v |= 1ull << ci;
        wb2[idx] = v;
    } else if (idx < 3072) {                           // w3: [256][128][4]
        int t = idx - 1024;
        int wdx = t & 1, k = (t >> 1) & 3, c = t >> 3;
        uint64_t v = 0;
        for (int ci = 0; ci < 64; ++ci)
            if (w3[((size_t)c * 128 + (wdx * 64 + ci)) * 4 + k] >= 0.f) v |= 1ull << ci;
        wb3[t] = v;
    } else if (idx < 9216) {                           // w5: [512][256][3]
        int t = idx - 3072;
        int wdx = t & 3, k = (t >> 2) % 3, c = t / 12;
        uint64_t v = 0;
        for (int ci = 0; ci < 64; ++ci)
            if (w5[((size_t)c * 256 + (wdx * 64 + ci)) * 3 + k] >= 0.f) v |= 1ull << ci;
        wb5[t] = v;
    } else if (idx < 9216 + 69720) {                   // wfc: [35][512*249] -> [oc][hh][wdx]
        int t = idx - 9216;
        int wdx = t & 7, hh = (t >> 3) % 249, oc = t / (249 * 8);
        uint64_t v = 0;
        for (int ci = 0; ci < 64; ++ci)
            if (wfc[(size_t)oc * 127488 + (size_t)(wdx * 64 + ci) * 249 + hh] >= 0.f)
                v |= 1ull << ci;
        wbf[t] = v;
    }
}

// ------------------------------- stage 1 ------------------------------------
// Fused conv1 (stride 4, K=84) computed per row-pair j (rows 2j, 2j+1).
// sign_mode==0: per-channel (sum, sumsq) partials (deterministic wave slices).
// sign_mode==1: BN (exact ref rounding order) + sign + maxpool(2,1) + bitpack;
//               lane j accumulates its 64-channel word in a register.
// blockIdx.z selects the channel half (word): cg in [16z, 16z+16).
__global__ __launch_bounds__(256) void conv1_fused(
    const float* __restrict__ x, const float* __restrict__ w1,
    const float* __restrict__ b1, const float2* __restrict__ bnp,
    const float* __restrict__ g, const float* __restrict__ be,
    float* __restrict__ part, uint64_t* __restrict__ a1, const int sign_mode)
{
    __shared__ float4 xe[268], xo[268];     // x4 even/odd split: lane stride 16 B
    __shared__ float  statw[4][128];        // per-wave (sum,sumsq) slices
    const int n    = blockIdx.y;
    const int j0   = blockIdx.x << 8;       // 256 row-pairs per block
    const int z    = blockIdx.z;            // channel word (0/1)
    const int tid  = threadIdx.x;
    const int wave = tid >> 6, lane = tid & 63;

    if (!sign_mode)
        for (int i = tid; i < 512; i += 256) ((float*)statw)[i] = 0.f;

    const float4* x4 = (const float4*)x + (size_t)n * 4000;
    for (int i = tid; i < 532; i += 256) {
        int gi = 2 * j0 + i;
        float4 v = (gi < 4000) ? x4[gi] : make_float4(0.f, 0.f, 0.f, 0.f);
        if (i & 1) xo[i >> 1] = v; else xe[i >> 1] = v;
    }
    __syncthreads();

    const int  jl    = tid;
    const int  j     = j0 + jl;
    const bool valid = j < J1;
    uint64_t bits = 0;

    for (int cgi = 0; cgi < 16; ++cgi) {
        const int cg = z * 16 + cgi;
        float acc0[4] = {0.f, 0.f, 0.f, 0.f};
        float acc1[4] = {0.f, 0.f, 0.f, 0.f};
        const float* wrow = w1 + cg * 4 * 84;
        #pragma unroll
        for (int kg = 0; kg < 21; ++kg) {
            float sw[4][4];                              // block-uniform (SGPR)
            #pragma unroll
            for (int ch = 0; ch < 4; ++ch)
                #pragma unroll
                for (int jj = 0; jj < 4; ++jj) {
                    float wv = wrow[ch * 84 + kg * 4 + jj];
                    sw[ch][jj] = (wv >= 0.f) ? 0.1f : -0.1f;
                }
            float4 xa, xb;                               // row 2j tap / row 2j+1 tap
            if (kg & 1) { xa = xo[jl + (kg - 1) / 2]; xb = xe[jl + (kg + 1) / 2]; }
            else        { xa = xe[jl + kg / 2];       xb = xo[jl + kg / 2]; }
            const float xav[4] = {xa.x, xa.y, xa.z, xa.w};
            const float xbv[4] = {xb.x, xb.y, xb.z, xb.w};
            #pragma unroll
            for (int jj = 0; jj < 4; ++jj)               // same chain order as R1
                #pragma unroll
                for (int ch = 0; ch < 4; ++ch) {
                    acc0[ch] = fmaf(sw[ch][jj], xav[jj], acc0[ch]);
                    acc1[ch] = fmaf(sw[ch][jj], xbv[jj], acc1[ch]);
                }
        }
        #pragma unroll
        for (int ch = 0; ch < 4; ++ch) {
            const int c = cg * 4 + ch;
            const float bv = b1[c];
            float v0 = acc0[ch] + bv;
            float v1 = acc1[ch] + bv;
            if (!valid) { v0 = 0.f; v1 = 0.f; }
            if (sign_mode) {
                const float2 mi = bnp[c];
                const float gg = g[c], bbe = be[c];
                float t0 = __fadd_rn(__fmul_rn(__fmul_rn(__fsub_rn(v0, mi.x), mi.y), gg), bbe);
                float t1 = __fadd_rn(__fmul_rn(__fmul_rn(__fsub_rn(v1, mi.x), mi.y), gg), bbe);
                if ((t0 >= 0.f) || (t1 >= 0.f)) bits |= 1ull << (c & 63);
            } else {
                float s = v0 + v1;
                float q = fmaf(v1, v1, fmaf(v0, v0, 0.f));
                #pragma unroll
                for (int o = 32; o > 0; o >>= 1) {
                    s += __shfl_xor(s, o, 64);
                    q += __shfl_xor(q, o, 64);
                }
                if (lane == 0) {
                    statw[wave][(cgi * 4 + ch) * 2 + 0] += s;
                    statw[wave][(cgi * 4 + ch) * 2 + 1] += q;
                }
            }
        }
    }

    if (sign_mode) {
        if (valid) a1[((size_t)n * J1 + j) * 2 + z] = bits;
    } else {
        __syncthreads();
        if (tid < 128) {
            float v = ((statw[0][tid] + statw[1][tid]) + statw[2][tid]) + statw[3][tid];
            part[((size_t)((n * 8 + blockIdx.x) * 2 + z)) * 128 + tid] = v;
        }
    }
}

// Parallel BN-stat reduce for stage 1: one block per channel (128 blocks).
// part layout: [512 part-blocks][z][64 ch][2]; channel c -> z=c>>6, cl=c&63.
__global__ __launch_bounds__(256) void bn_reduce1(const float* __restrict__ part,
                                                  float2* __restrict__ bnp)
{
    __shared__ double sS[256], sQ[256];
    const int c = blockIdx.x, t = threadIdx.x;
    const int z = c >> 6, cl = c & 63;
    double S = 0.0, SS = 0.0;
    for (int b = t; b < 512; b += 256) {
        const float2 p = *(const float2*)(part + ((size_t)(b * 2 + z)) * 128 + cl * 2);
        S += (double)p.x; SS += (double)p.y;
    }
    sS[t] = S; sQ[t] = SS;
    __syncthreads();
    for (int o = 128; o > 0; o >>= 1) {
        if (t < o) { sS[t] += sS[t + o]; sQ[t] += sQ[t + o]; }
        __syncthreads();
    }
    if (t == 0) {
        const double N = (double)Bn * H1;
        double mu  = sS[0] / N;
        double var = sQ[0] / N - mu * mu;
        bnp[c] = make_float2((float)mu, (float)(1.0 / sqrt(var + 1e-5)));
    }
}

// --------------------------- binary convs ----------------------------------
// q = 64*CINW*V - 2*popc(a xor w) over valid taps; y = 0.1*q + b (exact int q)
template<int CINW, int KK, int PAD, int COUT>
__global__ __launch_bounds__(COUT) void bconv(
    const uint64_t* __restrict__ ain, const uint64_t* __restrict__ wb,
    const int HIN, const int HOUT,
    int16_t* __restrict__ qout, int* __restrict__ part)
{
    __shared__ uint64_t rows[(64 + KK - 1) * CINW];
    const int n  = blockIdx.y;
    const int h0 = blockIdx.x << 6;
    const int c  = threadIdx.x;
    for (int i = c; i < (64 + KK - 1) * CINW; i += COUT) {
        int r = h0 - PAD + i / CINW;
        rows[i] = (r >= 0 && r < HIN) ? ain[((size_t)n * HIN + r) * CINW + (i % CINW)] : 0ull;
    }
    __syncthreads();
    uint64_t wreg[KK * CINW];
    #pragma unroll
    for (int i = 0; i < KK * CINW; ++i) wreg[i] = wb[(size_t)c * KK * CINW + i];
    int sq = 0, sq2 = 0;
    const int hmax = min(64, HOUT - h0);
    for (int i = 0; i < hmax; ++i) {
        const int h   = h0 + i;
        const int klo = max(0, PAD - h);
        const int khi = min(KK, HIN + PAD - h);
        int X = 0;
        if (klo == 0 && khi == KK) {
            #pragma unroll
            for (int k = 0; k < KK; ++k)
                #pragma unroll
                for (int wd = 0; wd < CINW; ++wd)
                    X += __popcll(rows[(i + k) * CINW + wd] ^ wreg[k * CINW + wd]);
        } else {
            for (int k = klo; k < khi; ++k)
                #pragma unroll
                for (int wd = 0; wd < CINW; ++wd)
                    X += __popcll(rows[(i + k) * CINW + wd] ^ wreg[k * CINW + wd]);
        }
        const int q = 64 * CINW * (khi - klo) - 2 * X;
        qout[((size_t)n * HOUT + h) * COUT + c] = (int16_t)q;
        sq += q; sq2 += q * q;
    }
    const size_t blk = (size_t)n * gridDim.x + blockIdx.x;
    part[(blk * COUT + c) * 2 + 0] = sq;
    part[(blk * COUT + c) * 2 + 1] = sq2;
}

// Parallel q-stat reduce: one block per channel; integer sums are exact and
// order-independent, so the tree order is bit-identical to any serial order.
__global__ __launch_bounds__(256) void bn_reduce_q(
    const int* __restrict__ part, const int nblk, const int C,
    const double N, const float* __restrict__ bias, float2* __restrict__ bnp)
{
    __shared__ long long sS[256], sQ[256];
    const int c = blockIdx.x, t = threadIdx.x;
    long long Sq = 0, Sq2 = 0;
    for (int b = t; b < nblk; b += 256) {
        const int2 p = *(const int2*)(part + ((size_t)b * C + c) * 2);
        Sq += p.x; Sq2 += p.y;
    }
    sS[t] = Sq; sQ[t] = Sq2;
    __syncthreads();
    for (int o = 128; o > 0; o >>= 1) {
        if (t < o) { sS[t] += sS[t + o]; sQ[t] += sQ[t + o]; }
        __syncthreads();
    }
    if (t == 0) {
        const double bb = (double)bias[c];
        const double S  = 0.1 * (double)sS[0] + N * bb;              // sum(y), exact
        const double SS = 0.01 * (double)sQ[0] + 0.2 * bb * (double)sS[0] + N * bb * bb;
        const double mu = S / N;
        const double var = SS / N - mu * mu;
        bnp[c] = make_float2((float)mu, (float)(1.0 / sqrt(var + 1e-5)));
    }
}

template<int W>
__global__ void signpool_q(const int16_t* __restrict__ q, const float* __restrict__ bias,
                           const float2* __restrict__ bnp, const float* __restrict__ g,
                           const float* __restrict__ be, const int H, const int J,
                           uint64_t* __restrict__ aout)
{
    const int n  = blockIdx.y;
    const int j0 = blockIdx.x << 6;
    const int wave = threadIdx.x >> 6, lane = threadIdx.x & 63;
    const int nw = blockDim.x >> 6;
    const int C  = W * 64;
    const int jend = min(j0 + 64, J);
    for (int w = wave; w < W; w += nw) {
        const int c = (w << 6) + lane;
        const float2 mi = bnp[c];
        const float bb = bias[c], gg = g[c], bbe = be[c];
        for (int j = j0; j < jend; ++j) {
            float y0 = __fadd_rn(__fmul_rn(0.1f, (float)q[((size_t)n * H + 2 * j    ) * C + c]), bb);
            float y1v= __fadd_rn(__fmul_rn(0.1f, (float)q[((size_t)n * H + 2 * j + 1) * C + c]), bb);
            float t0 = __fadd_rn(__fmul_rn(__fmul_rn(__fsub_rn(y0,  mi.x), mi.y), gg), bbe);
            float t1 = __fadd_rn(__fmul_rn(__fmul_rn(__fsub_rn(y1v, mi.x), mi.y), gg), bbe);
            uint64_t word = __ballot((t0 >= 0.f) || (t1 >= 0.f));
            if (lane == 0) aout[((size_t)n * J + j) * W + w] = word;
        }
    }
}

// ------------------------------- FC ----------------------------------------
__global__ void fc_kernel(const uint64_t* __restrict__ a5, const uint64_t* __restrict__ wfcb,
                          float* __restrict__ out)
{
    const int n    = blockIdx.y;
    const int oc   = blockIdx.x * 4 + (threadIdx.x >> 6);
    const int lane = threadIdx.x & 63;
    if (oc >= 35) return;
    const uint64_t* arow = a5   + (size_t)n  * FCW;
    const uint64_t* wrow = wfcb + (size_t)oc * FCW;
    int X = 0;
    for (int i = lane; i < FCW; i += 64)
        X += __popcll(arow[i] ^ wrow[i]);
    for (int o = 32; o > 0; o >>= 1) X += __shfl_xor(X, o, 64);
    if (lane == 0) out[(size_t)n * 35 + oc] = 0.1f * (float)(127488 - 2 * X);
}

// ---------------------------------------------------------------------------
extern "C" void kernel_launch(void* const* d_in, const int* in_sizes, int n_in,
                              void* d_out, int out_size, void* d_ws, size_t ws_size,
                              hipStream_t stream)
{
    (void)in_sizes; (void)n_in; (void)out_size;
    const float* x   = (const float*)d_in[0];
    const float* w1  = (const float*)d_in[1];
    const float* b1  = (const float*)d_in[2];
    const float* g1  = (const float*)d_in[3];
    const float* be1 = (const float*)d_in[4];
    const float* w2  = (const float*)d_in[5];
    const float* b2  = (const float*)d_in[6];
    const float* g2  = (const float*)d_in[7];
    const float* be2 = (const float*)d_in[8];
    const float* w3  = (const float*)d_in[9];
    const float* b3  = (const float*)d_in[10];
    const float* g3  = (const float*)d_in[11];
    const float* be3 = (const float*)d_in[12];
    const float* w5  = (const float*)d_in[13];
    const float* b5  = (const float*)d_in[14];
    const float* g5  = (const float*)d_in[15];
    const float* be5 = (const float*)d_in[16];
    const float* wfc = (const float*)d_in[17];
    char* ws = (char*)d_ws;

    size_t cur = 0;
    auto take = [&](size_t bytes) {
        size_t r = cur;
        cur = (cur + bytes + 255) & ~(size_t)255;
        return r;
    };
    int16_t*  qb  = (int16_t*)(ws + take(33554432));   // stage q buffer (<=32.7 MB)
    int*      pq  = (int*)(ws + take(4194304));        // bconv stat partials
    uint64_t* a1  = (uint64_t*)(ws + take(2037760));
    uint64_t* a2  = (uint64_t*)(ws + take(1018880));
    uint64_t* a3  = (uint64_t*)(ws + take(1017856));
    uint64_t* a5  = (uint64_t*)(ws + take(1019904));
    uint64_t* wb2 = (uint64_t*)(ws + take(8192));
    uint64_t* wb3 = (uint64_t*)(ws + take(16384));
    uint64_t* wb5 = (uint64_t*)(ws + take(49152));
    uint64_t* wbf = (uint64_t*)(ws + take(557760));
    float*    p1  = (float*)(ws + take(524288));       // 1024 blocks x 128 floats
    float2*   bnp1 = (float2*)(ws + take(1024));
    float2*   bnp2 = (float2*)(ws + take(1024));
    float2*   bnp3 = (float2*)(ws + take(2048));
    float2*   bnp5 = (float2*)(ws + take(4096));
    if (cur > ws_size) return;   // insufficient workspace -> fail loudly

    hipLaunchKernelGGL(binarize_all, dim3(309), dim3(256), 0, stream,
                       w2, w3, w5, wfc, wb2, wb3, wb5, wbf);
    // stage 1: stats pass, reduce, sign pass (no y1 materialization)
    hipLaunchKernelGGL(conv1_fused, dim3(8, 64, 2), dim3(256), 0, stream,
                       x, w1, b1, (const float2*)nullptr, g1, be1, p1, a1, 0);
    hipLaunchKernelGGL(bn_reduce1, dim3(128), dim3(256), 0, stream, p1, bnp1);
    hipLaunchKernelGGL(conv1_fused, dim3(8, 64, 2), dim3(256), 0, stream,
                       x, w1, b1, bnp1, g1, be1, p1, a1, 1);
    // stage 2
    hipLaunchKernelGGL((bconv<2, 4, 2, 128>), dim3(32, 64), dim3(128), 0, stream,
                       a1, wb2, J1, H2o, qb, pq);
    hipLaunchKernelGGL(bn_reduce_q, dim3(128), dim3(256), 0, stream,
                       pq, 2048, 128, (double)Bn * H2o, b2, bnp2);
    hipLaunchKernelGGL((signpool_q<2>), dim3(16, 64), dim3(128), 0, stream,
                       qb, b2, bnp2, g2, be2, H2o, J2, a2);
    // stage 3
    hipLaunchKernelGGL((bconv<2, 4, 1, 256>), dim3(16, 64), dim3(256), 0, stream,
                       a2, wb3, J2, H3o, qb, pq);
    hipLaunchKernelGGL(bn_reduce_q, dim3(256), dim3(256), 0, stream,
                       pq, 1024, 256, (double)Bn * H3o, b3, bnp3);
    hipLaunchKernelGGL((signpool_q<4>), dim3(8, 64), dim3(256), 0, stream,
                       qb, b3, bnp3, g3, be3, H3o, J3, a3);
    // stage 5
    hipLaunchKernelGGL((bconv<4, 3, 2, 512>), dim3(8, 64), dim3(512), 0, stream,
                       a3, wb5, J3, H5o, qb, pq);
    hipLaunchKernelGGL(bn_reduce_q, dim3(512), dim3(256), 0, stream,
                       pq, 512, 512, (double)Bn * H5o, b5, bnp5);
    hipLaunchKernelGGL((signpool_q<8>), dim3(4, 64), dim3(256), 0, stream,
                       qb, b5, bnp5, g5, be5, H5o, J5, a5);
    // FC
    hipLaunchKernelGGL(fc_kernel, dim3(9, 64), dim3(256), 0, stream,
                       a5, wbf, (float*)d_out);
}